// Round 1
// baseline (193.232 us; speedup 1.0000x reference)
//
#include <hip/hip_runtime.h>
#include <hip/hip_bf16.h>

#define T_STEPS 8192
#define NN 64
#define FF 128
#define HH 128
#define OO 128
#define TPB_T 4

typedef _Float16 f16;
typedef __attribute__((ext_vector_type(8))) _Float16 f16x8;
typedef __attribute__((ext_vector_type(4))) _Float16 f16x4;
typedef __attribute__((ext_vector_type(4))) float f32x4;

// LDS pitches chosen for <=2-way bank aliasing on ds_read_b128 (free per m136)
#define XH_PITCH 136   // f16 units; 272 B rows, 16B-aligned
#define H2_PITCH 72    // f16 units; 144 B rows, 16B-aligned

// ---------------- prep: norm (f16), c (f32) ----------------
__global__ void prep_norm_kernel(const int* __restrict__ src, const int* __restrict__ dst, int E,
                                 const float* __restrict__ benc, const float* __restrict__ wgcn,
                                 const float* __restrict__ bgcn,
                                 f16* __restrict__ normg, float* __restrict__ cg)
{
    __shared__ float A[NN * NN];
    __shared__ float din[NN], dout[NN], rs[NN], bc[OO];
    const int tid = threadIdx.x;
    for (int i = tid; i < NN * NN; i += 256) A[i] = 0.0f;
    __syncthreads();
    for (int e = tid; e < E; e += 256) atomicAdd(&A[dst[e] * NN + src[e]], 1.0f);
    __syncthreads();
    if (tid < NN) A[tid * NN + tid] += 1.0f;
    __syncthreads();
    if (tid < NN) {               // deg_in[i] = row sum
        float s = 0.f;
        for (int j = 0; j < NN; ++j) s += A[tid * NN + j];
        din[tid] = s;
    } else if (tid < 2 * NN) {    // deg_out[j] = col sum
        int j = tid - NN;
        float s = 0.f;
        for (int i = 0; i < NN; ++i) s += A[i * NN + j];
        dout[j] = s;
    }
    __syncthreads();
    if (tid < NN) {
        float ri = rsqrtf(din[tid]);
        float s = 0.f;
        for (int j = 0; j < NN; ++j) {
            float v = A[tid * NN + j] * ri * rsqrtf(dout[j]);
            s += v;
            normg[tid * NN + j] = (f16)v;
        }
        rs[tid] = s;
    }
    if (tid >= 128 && tid < 128 + OO) {   // bc[o] = b_enc @ W_gcn
        int o = tid - 128;
        float s = 0.f;
        for (int h = 0; h < HH; ++h) s += benc[h] * wgcn[h * OO + o];
        bc[o] = s;
    }
    __syncthreads();
    for (int idx = tid; idx < NN * OO; idx += 256) {
        int i = idx >> 7, o = idx & 127;
        cg[idx] = rs[i] * bc[o] + bgcn[o];
    }
}

// ---------------- prep: WcT[o][f] = (W_enc @ W_gcn)^T (f16) ----------------
__global__ void prep_wc_kernel(const float* __restrict__ wenc, const float* __restrict__ wgcn,
                               f16* __restrict__ wctg)
{
    int o = blockIdx.x * 2 + (threadIdx.x >> 7);
    int f = threadIdx.x & 127;
    float s = 0.f;
    for (int h = 0; h < HH; ++h) s += wenc[f * HH + h] * wgcn[h * OO + o];
    wctg[o * FF + f] = (f16)s;
}

// ---------------- fused main: out[t] = norm @ (x[t] @ Wc) + c ----------------
__global__ __launch_bounds__(256, 2) void fused_kernel(
    const float* __restrict__ x, const f16* __restrict__ normg,
    const f16* __restrict__ wctg, const float* __restrict__ cg,
    float* __restrict__ out)
{
    __shared__ f16 xh[NN * XH_PITCH];    // x_t as f16, padded  (17408 B)
    __shared__ f16 h2t[OO * H2_PITCH];   // h2 transposed [col][node] (18432 B)

    const int tid = threadIdx.x;
    const int lane = tid & 63;
    const int w = tid >> 6;        // wave 0..3 -> output cols w*32..w*32+31
    const int l15 = lane & 15;
    const int lg = lane >> 4;      // 0..3

    // loop-invariant fragments in registers
    f16x8 wcf[2][4];               // B-frags of Wc for this wave's col slice
#pragma unroll
    for (int ct = 0; ct < 2; ++ct)
#pragma unroll
        for (int kk = 0; kk < 4; ++kk)
            wcf[ct][kk] = *(const f16x8*)(wctg + (w * 32 + ct * 16 + l15) * FF + kk * 32 + lg * 8);

    f16x8 nf[4][2];                // A-frags of norm (all row tiles)
#pragma unroll
    for (int rt = 0; rt < 4; ++rt)
#pragma unroll
        for (int kk = 0; kk < 2; ++kk)
            nf[rt][kk] = *(const f16x8*)(normg + (rt * 16 + l15) * NN + kk * 32 + lg * 8);

    float cf[4][2][4];             // bias frags (fp32)
#pragma unroll
    for (int rt = 0; rt < 4; ++rt)
#pragma unroll
        for (int ct = 0; ct < 2; ++ct)
#pragma unroll
            for (int r = 0; r < 4; ++r)
                cf[rt][ct][r] = cg[(rt * 16 + lg * 4 + r) * OO + w * 32 + ct * 16 + l15];

    const int t0 = blockIdx.x * TPB_T;

    // prologue prefetch of x[t0] into registers (8 x float4 = entire block covers 32 KB)
    float4 ra[8];
    {
        const float4* xp = (const float4*)(x + (size_t)t0 * (NN * FF));
#pragma unroll
        for (int ii = 0; ii < 4; ++ii) {
            int c = tid + 256 * ii;
            ra[2 * ii]     = xp[2 * c];
            ra[2 * ii + 1] = xp[2 * c + 1];
        }
    }

    for (int i = 0; i < TPB_T; ++i) {
        const int t = t0 + i;

        // S1: convert + stage x_t into LDS (vmcnt wait on ra happens here)
#pragma unroll
        for (int ii = 0; ii < 4; ++ii) {
            int c = tid + 256 * ii;
            int row = c >> 4, k0 = (c & 15) * 8;
            float4 a = ra[2 * ii], b = ra[2 * ii + 1];
            f16x8 v;
            v[0] = (f16)a.x; v[1] = (f16)a.y; v[2] = (f16)a.z; v[3] = (f16)a.w;
            v[4] = (f16)b.x; v[5] = (f16)b.y; v[6] = (f16)b.z; v[7] = (f16)b.w;
            *(f16x8*)(xh + row * XH_PITCH + k0) = v;
        }
        __syncthreads();   // xh ready for all waves

        // S3: issue next t's global loads early (hide HBM latency under MFMA)
        if (i + 1 < TPB_T) {
            const float4* xq = (const float4*)(x + (size_t)(t + 1) * (NN * FF));
#pragma unroll
            for (int ii = 0; ii < 4; ++ii) {
                int c = tid + 256 * ii;
                ra[2 * ii]     = xq[2 * c];
                ra[2 * ii + 1] = xq[2 * c + 1];
            }
        }

        // S4: matmul1  h2[64, w-cols] = x_t @ Wc
        f32x4 acc1[4][2] = {};
#pragma unroll
        for (int kk = 0; kk < 4; ++kk) {
            f16x8 af[4];
#pragma unroll
            for (int rt = 0; rt < 4; ++rt)
                af[rt] = *(const f16x8*)(xh + (rt * 16 + l15) * XH_PITCH + kk * 32 + lg * 8);
#pragma unroll
            for (int rt = 0; rt < 4; ++rt)
#pragma unroll
                for (int ct = 0; ct < 2; ++ct)
                    acc1[rt][ct] = __builtin_amdgcn_mfma_f32_16x16x32_f16(
                        af[rt], wcf[ct][kk], acc1[rt][ct], 0, 0, 0);
        }
        __syncthreads();   // all waves done reading xh -> safe to overwrite next iter

        // S5: per-wave transpose h2 -> LDS [col][node] (wave-private slice, no barrier needed)
#pragma unroll
        for (int rt = 0; rt < 4; ++rt)
#pragma unroll
            for (int ct = 0; ct < 2; ++ct) {
                f16x4 hv;
#pragma unroll
                for (int r = 0; r < 4; ++r) hv[r] = (f16)acc1[rt][ct][r];
                *(f16x4*)(h2t + (w * 32 + ct * 16 + l15) * H2_PITCH + rt * 16 + lg * 4) = hv;
            }

        // S7: matmul2  out_t[64, w-cols] = norm @ h2
        f32x4 acc2[4][2] = {};
#pragma unroll
        for (int kk = 0; kk < 2; ++kk) {
            f16x8 bf[2];
#pragma unroll
            for (int ct = 0; ct < 2; ++ct)
                bf[ct] = *(const f16x8*)(h2t + (w * 32 + ct * 16 + l15) * H2_PITCH + kk * 32 + lg * 8);
#pragma unroll
            for (int rt = 0; rt < 4; ++rt)
#pragma unroll
                for (int ct = 0; ct < 2; ++ct)
                    acc2[rt][ct] = __builtin_amdgcn_mfma_f32_16x16x32_f16(
                        nf[rt][kk], bf[ct], acc2[rt][ct], 0, 0, 0);
        }

        // epilogue: add bias, store fp32
        float* op = out + (size_t)t * (NN * OO);
#pragma unroll
        for (int rt = 0; rt < 4; ++rt)
#pragma unroll
            for (int ct = 0; ct < 2; ++ct)
#pragma unroll
                for (int r = 0; r < 4; ++r)
                    op[(rt * 16 + lg * 4 + r) * OO + w * 32 + ct * 16 + l15] =
                        acc2[rt][ct][r] + cf[rt][ct][r];
    }
}

extern "C" void kernel_launch(void* const* d_in, const int* in_sizes, int n_in,
                              void* d_out, int out_size, void* d_ws, size_t ws_size,
                              hipStream_t stream)
{
    const float* x    = (const float*)d_in[0];
    const float* wenc = (const float*)d_in[1];
    const float* benc = (const float*)d_in[2];
    const float* wgcn = (const float*)d_in[3];
    const float* bgcn = (const float*)d_in[4];
    const int*   src  = (const int*)d_in[5];
    const int*   dst  = (const int*)d_in[6];
    const int E = in_sizes[5];

    // workspace layout: norm f16 [64*64] | WcT f16 [128*128] | c f32 [64*128]
    f16*   normg = (f16*)d_ws;
    f16*   wctg  = (f16*)((char*)d_ws + NN * NN * sizeof(f16));
    float* cg    = (float*)((char*)d_ws + NN * NN * sizeof(f16) + OO * FF * sizeof(f16));

    prep_norm_kernel<<<1, 256, 0, stream>>>(src, dst, E, benc, wgcn, bgcn, normg, cg);
    prep_wc_kernel<<<OO / 2, 256, 0, stream>>>(wenc, wgcn, wctg);
    fused_kernel<<<T_STEPS / TPB_T, 256, 0, stream>>>(x, normg, wctg, cg, (float*)d_out);
}

// Round 2
// 133.028 us; speedup vs baseline: 1.4526x; 1.4526x over previous
//
#include <hip/hip_runtime.h>
#include <hip/hip_bf16.h>

#define T_STEPS 8192
#define NN 64
#define FF 128
#define HH 128
#define OO 128
#define TPB_T 4

typedef _Float16 f16;
typedef __attribute__((ext_vector_type(8))) _Float16 f16x8;
typedef __attribute__((ext_vector_type(4))) _Float16 f16x4;
typedef __attribute__((ext_vector_type(4))) float f32x4;

// LDS pitches chosen for <=2-way bank aliasing on ds_read_b128 (free per m136)
#define XH_PITCH 136   // f16 units; 272 B rows, 16B-aligned
#define H2_PITCH 72    // f16 units; 144 B rows, 16B-aligned

// ---------------- prep: norm (f16), c (f32) ----------------
__global__ void prep_norm_kernel(const int* __restrict__ src, const int* __restrict__ dst, int E,
                                 const float* __restrict__ benc, const float* __restrict__ wgcn,
                                 const float* __restrict__ bgcn,
                                 f16* __restrict__ normg, float* __restrict__ cg)
{
    __shared__ float A[NN * NN];
    __shared__ float din[NN], dout[NN], rs[NN], bc[OO];
    const int tid = threadIdx.x;
    for (int i = tid; i < NN * NN; i += 256) A[i] = 0.0f;
    __syncthreads();
    for (int e = tid; e < E; e += 256) atomicAdd(&A[dst[e] * NN + src[e]], 1.0f);
    __syncthreads();
    if (tid < NN) A[tid * NN + tid] += 1.0f;
    __syncthreads();
    if (tid < NN) {               // deg_in[i] = row sum
        float s = 0.f;
        for (int j = 0; j < NN; ++j) s += A[tid * NN + j];
        din[tid] = s;
    } else if (tid < 2 * NN) {    // deg_out[j] = col sum
        int j = tid - NN;
        float s = 0.f;
        for (int i = 0; i < NN; ++i) s += A[i * NN + j];
        dout[j] = s;
    }
    __syncthreads();
    if (tid < NN) {
        float ri = rsqrtf(din[tid]);
        float s = 0.f;
        for (int j = 0; j < NN; ++j) {
            float v = A[tid * NN + j] * ri * rsqrtf(dout[j]);
            s += v;
            normg[tid * NN + j] = (f16)v;
        }
        rs[tid] = s;
    }
    if (tid >= 128 && tid < 128 + OO) {   // bc[o] = b_enc @ W_gcn
        int o = tid - 128;
        float s = 0.f;
        for (int h = 0; h < HH; ++h) s += benc[h] * wgcn[h * OO + o];
        bc[o] = s;
    }
    __syncthreads();
    for (int idx = tid; idx < NN * OO; idx += 256) {
        int i = idx >> 7, o = idx & 127;
        cg[idx] = rs[i] * bc[o] + bgcn[o];
    }
}

// ---------------- prep: WcT[o][f] = (W_enc @ W_gcn)^T (f16) ----------------
__global__ void prep_wc_kernel(const float* __restrict__ wenc, const float* __restrict__ wgcn,
                               f16* __restrict__ wctg)
{
    int o = blockIdx.x * 2 + (threadIdx.x >> 7);
    int f = threadIdx.x & 127;
    float s = 0.f;
    for (int h = 0; h < HH; ++h) s += wenc[f * HH + h] * wgcn[h * OO + o];
    wctg[o * FF + f] = (f16)s;
}

// ---------------- fused main: out[t] = norm @ (x[t] @ Wc) + c ----------------
__global__ __launch_bounds__(256, 2) void fused_kernel(
    const float* __restrict__ x, const f16* __restrict__ normg,
    const f16* __restrict__ wctg, const float* __restrict__ cg,
    float* __restrict__ out)
{
    __shared__ f16 xh[NN * XH_PITCH];    // x_t as f16, padded  (17408 B)
    __shared__ f16 h2t[OO * H2_PITCH];   // h2 transposed [col][node] (18432 B)

    const int tid = threadIdx.x;
    const int lane = tid & 63;
    const int w = tid >> 6;        // wave 0..3 -> output cols w*32..w*32+31
    const int l15 = lane & 15;
    const int lg = lane >> 4;      // 0..3

    // loop-invariant fragments in registers
    f16x8 wcf[2][4];               // B-frags of Wc for this wave's col slice
#pragma unroll
    for (int ct = 0; ct < 2; ++ct)
#pragma unroll
        for (int kk = 0; kk < 4; ++kk)
            wcf[ct][kk] = *(const f16x8*)(wctg + (w * 32 + ct * 16 + l15) * FF + kk * 32 + lg * 8);

    f16x8 nf[4][2];                // norm frags; used as B in the swapped MFMA2 (norm^T)
#pragma unroll
    for (int rt = 0; rt < 4; ++rt)
#pragma unroll
        for (int kk = 0; kk < 2; ++kk)
            nf[rt][kk] = *(const f16x8*)(normg + (rt * 16 + l15) * NN + kk * 32 + lg * 8);

    // bias frags matching the TRANSPOSED acc2 layout: lane holds 4 consecutive cols of row rt*16+l15
    f32x4 cf2[4][2];
#pragma unroll
    for (int rt = 0; rt < 4; ++rt)
#pragma unroll
        for (int ct = 0; ct < 2; ++ct)
            cf2[rt][ct] = *(const f32x4*)(cg + (rt * 16 + l15) * OO + w * 32 + ct * 16 + lg * 4);

    const int t0 = blockIdx.x * TPB_T;

    // prologue prefetch of x[t0] into registers (8 x float4 = entire block covers 32 KB)
    float4 ra[8];
    {
        const float4* xp = (const float4*)(x + (size_t)t0 * (NN * FF));
#pragma unroll
        for (int ii = 0; ii < 4; ++ii) {
            int c = tid + 256 * ii;
            ra[2 * ii]     = xp[2 * c];
            ra[2 * ii + 1] = xp[2 * c + 1];
        }
    }

    for (int i = 0; i < TPB_T; ++i) {
        const int t = t0 + i;

        // S1: convert + stage x_t into LDS (vmcnt wait on ra happens here)
#pragma unroll
        for (int ii = 0; ii < 4; ++ii) {
            int c = tid + 256 * ii;
            int row = c >> 4, k0 = (c & 15) * 8;
            float4 a = ra[2 * ii], b = ra[2 * ii + 1];
            f16x8 v;
            v[0] = (f16)a.x; v[1] = (f16)a.y; v[2] = (f16)a.z; v[3] = (f16)a.w;
            v[4] = (f16)b.x; v[5] = (f16)b.y; v[6] = (f16)b.z; v[7] = (f16)b.w;
            *(f16x8*)(xh + row * XH_PITCH + k0) = v;
        }
        __syncthreads();   // xh ready for all waves

        // S3: issue next t's global loads early (hide HBM latency under MFMA)
        if (i + 1 < TPB_T) {
            const float4* xq = (const float4*)(x + (size_t)(t + 1) * (NN * FF));
#pragma unroll
            for (int ii = 0; ii < 4; ++ii) {
                int c = tid + 256 * ii;
                ra[2 * ii]     = xq[2 * c];
                ra[2 * ii + 1] = xq[2 * c + 1];
            }
        }

        // S4: matmul1  h2[64, w-cols] = x_t @ Wc
        f32x4 acc1[4][2] = {};
#pragma unroll
        for (int kk = 0; kk < 4; ++kk) {
            f16x8 af[4];
#pragma unroll
            for (int rt = 0; rt < 4; ++rt)
                af[rt] = *(const f16x8*)(xh + (rt * 16 + l15) * XH_PITCH + kk * 32 + lg * 8);
#pragma unroll
            for (int rt = 0; rt < 4; ++rt)
#pragma unroll
                for (int ct = 0; ct < 2; ++ct)
                    acc1[rt][ct] = __builtin_amdgcn_mfma_f32_16x16x32_f16(
                        af[rt], wcf[ct][kk], acc1[rt][ct], 0, 0, 0);
        }
        __syncthreads();   // all waves done reading xh -> safe to overwrite next iter

        // S5: per-wave transpose h2 -> LDS [col][node] (wave-private slice, no barrier needed)
#pragma unroll
        for (int rt = 0; rt < 4; ++rt)
#pragma unroll
            for (int ct = 0; ct < 2; ++ct) {
                f16x4 hv;
#pragma unroll
                for (int r = 0; r < 4; ++r) hv[r] = (f16)acc1[rt][ct][r];
                *(f16x4*)(h2t + (w * 32 + ct * 16 + l15) * H2_PITCH + rt * 16 + lg * 4) = hv;
            }

        // S7: matmul2 with SWAPPED operands: D = h2^T * norm^T  ->  D[m=C][n=R] = out[R][C]
        // Same fragment loads as the un-swapped version; only operand order changes.
        // Resulting lane layout: lane(l15,lg) holds out[rt*16+l15][w*32+ct*16+lg*4 .. +3]
        f32x4 acc2[2][4] = {};
#pragma unroll
        for (int kk = 0; kk < 2; ++kk) {
            f16x8 bf[2];
#pragma unroll
            for (int ct = 0; ct < 2; ++ct)
                bf[ct] = *(const f16x8*)(h2t + (w * 32 + ct * 16 + l15) * H2_PITCH + kk * 32 + lg * 8);
#pragma unroll
            for (int ct = 0; ct < 2; ++ct)
#pragma unroll
                for (int rt = 0; rt < 4; ++rt)
                    acc2[ct][rt] = __builtin_amdgcn_mfma_f32_16x16x32_f16(
                        bf[ct], nf[rt][kk], acc2[ct][rt], 0, 0, 0);
        }

        // epilogue: add bias, store fp32 as float4 (full 128B line per row per wave, ct back-to-back)
        float* op = out + (size_t)t * (NN * OO);
#pragma unroll
        for (int rt = 0; rt < 4; ++rt)
#pragma unroll
            for (int ct = 0; ct < 2; ++ct) {
                f32x4 v = acc2[ct][rt] + cf2[rt][ct];
                *(f32x4*)(op + (rt * 16 + l15) * OO + w * 32 + ct * 16 + lg * 4) = v;
            }
    }
}

extern "C" void kernel_launch(void* const* d_in, const int* in_sizes, int n_in,
                              void* d_out, int out_size, void* d_ws, size_t ws_size,
                              hipStream_t stream)
{
    const float* x    = (const float*)d_in[0];
    const float* wenc = (const float*)d_in[1];
    const float* benc = (const float*)d_in[2];
    const float* wgcn = (const float*)d_in[3];
    const float* bgcn = (const float*)d_in[4];
    const int*   src  = (const int*)d_in[5];
    const int*   dst  = (const int*)d_in[6];
    const int E = in_sizes[5];

    // workspace layout: norm f16 [64*64] | WcT f16 [128*128] | c f32 [64*128]
    f16*   normg = (f16*)d_ws;
    f16*   wctg  = (f16*)((char*)d_ws + NN * NN * sizeof(f16));
    float* cg    = (float*)((char*)d_ws + NN * NN * sizeof(f16) + OO * FF * sizeof(f16));

    prep_norm_kernel<<<1, 256, 0, stream>>>(src, dst, E, benc, wgcn, bgcn, normg, cg);
    prep_wc_kernel<<<OO / 2, 256, 0, stream>>>(wenc, wgcn, wctg);
    fused_kernel<<<T_STEPS / TPB_T, 256, 0, stream>>>(x, normg, wctg, cg, (float*)d_out);
}